// Round 12
// baseline (1187.002 us; speedup 1.0000x reference)
//
#include <hip/hip_runtime.h>

#define N_NODES 50000
#define N_EDGES 800000
#define D_IN    64
#define D_HID   128
#define NBLK    ((N_NODES + 255) / 256)   // 196

__device__ __forceinline__ float bf2f(unsigned short u) {
    return __uint_as_float(((unsigned)u) << 16);
}
__device__ __forceinline__ unsigned short f2bf(float f) {
    unsigned u = __float_as_uint(f);
    return (unsigned short)((u + 0x7FFFu + ((u >> 16) & 1u)) >> 16);
}

// ---- CSR build ----
__global__ void k_count(const int* __restrict__ rcv, int* __restrict__ deg) {
    int i = blockIdx.x * blockDim.x + threadIdx.x;
    if (i < N_EDGES) atomicAdd(&deg[rcv[i]], 1);
}

__global__ void k_blocksum(const int* __restrict__ deg, int* __restrict__ bsum) {
    int b = blockIdx.x, t = threadIdx.x;
    int i = b * 256 + t;
    int v = (i < N_NODES) ? deg[i] : 0;
#pragma unroll
    for (int o = 32; o >= 1; o >>= 1) v += __shfl_down(v, o);
    __shared__ int s[4];
    if ((t & 63) == 0) s[t >> 6] = v;
    __syncthreads();
    if (t == 0) bsum[b] = s[0] + s[1] + s[2] + s[3];
}

__global__ void k_scanb(const int* __restrict__ bsum, int* __restrict__ boff) {
    __shared__ int sh[256];
    int t = threadIdx.x;
    int v = (t < NBLK) ? bsum[t] : 0;
    sh[t] = v;
    __syncthreads();
    for (int d = 1; d < 256; d <<= 1) {
        int u = (t >= d) ? sh[t - d] : 0;
        __syncthreads();
        sh[t] += u;
        __syncthreads();
    }
    boff[t] = sh[t] - v;   // exclusive
}

__global__ void k_offsets(const int* __restrict__ deg, const int* __restrict__ boff,
                          int* __restrict__ off, int* __restrict__ cursor,
                          float* __restrict__ inv) {
    __shared__ int sh[256];
    int b = blockIdx.x, t = threadIdx.x, i = b * 256 + t;
    int d = (i < N_NODES) ? deg[i] : 0;
    sh[t] = d;
    __syncthreads();
    for (int o = 1; o < 256; o <<= 1) {
        int u = (t >= o) ? sh[t - o] : 0;
        __syncthreads();
        sh[t] += u;
        __syncthreads();
    }
    if (i < N_NODES) {
        int excl = boff[b] + sh[t] - d;
        off[i] = excl;
        cursor[i] = excl;
        inv[i] = d > 0 ? 1.0f / (float)d : 0.0f;
    }
    if (b == 0 && t == 0) off[N_NODES] = N_EDGES;
}

__global__ void k_fill(const int* __restrict__ snd, const int* __restrict__ rcv,
                       const float* __restrict__ w,
                       int* __restrict__ cursor,
                       int* __restrict__ e_snd, float* __restrict__ e_w) {
    int i = blockIdx.x * blockDim.x + threadIdx.x;
    if (i >= N_EDGES) return;
    int r = rcv[i];
    int p = atomicAdd(&cursor[r], 1);
    e_snd[p] = snd[i];
    e_w[p]   = w[i];
}

// ---- fp32 -> bf16 (RNE) pair-packed conversion ----
__global__ void k_tobf(const float* __restrict__ src, unsigned int* __restrict__ dst,
                       int npairs) {
    int i = blockIdx.x * blockDim.x + threadIdx.x;
    if (i >= npairs) return;
    float2 v = *(const float2*)(src + (size_t)i * 2);
    dst[i] = (unsigned)f2bf(v.x) | ((unsigned)f2bf(v.y) << 16);
}

// ---- fused layer (r7 access pattern + sender-slab passes) ----
// One wave per node; lane l holds feature(s) l (+64k). The edge list is
// scanned NPASS times; pass p accumulates only senders in slab p (1.6 MB of
// bf16 rows -> fits every XCD's 4 MB L2, converting random fabric traffic
// into L2 hits). Slab test is wave-uniform (scalar branch, no divergence).
template<int DIN, int DOUT, bool RELU, bool DO_MLP>
__global__ __launch_bounds__(256) void k_layer(
        const float* __restrict__ h,
        const unsigned short* __restrict__ hb,
        const int* __restrict__ off,
        const int* __restrict__ e_snd,
        const float* __restrict__ e_w,
        const float* __restrict__ inv,
        const float* __restrict__ eps, int li,
        const float* __restrict__ W,
        const float* __restrict__ b,
        float* __restrict__ out) {
    constexpr int K = DIN / 64;
    constexpr int NPASS = 8;
    constexpr int SLAB  = (N_NODES + NPASS - 1) / NPASS;   // 6250
    int wave = threadIdx.x >> 6;
    int lane = threadIdx.x & 63;
    int n = blockIdx.x * (blockDim.x >> 6) + wave;
    if (n >= N_NODES) return;

    float pool[K];
#pragma unroll
    for (int k = 0; k < K; ++k) pool[k] = 0.0f;

    int e0 = off[n], e1 = off[n + 1];
    for (int p = 0; p < NPASS; ++p) {
        int lo = p * SLAB, hi = lo + SLAB;
        for (int e = e0; e < e1; ++e) {
            int s0 = e_snd[e];                   // wave-uniform scalar load
            if (s0 >= lo && s0 < hi) {           // wave-uniform branch
                float w0 = e_w[e];
                const unsigned short* p0 = hb + (size_t)s0 * DIN;
#pragma unroll
                for (int k = 0; k < K; ++k)
                    pool[k] += bf2f(p0[lane + 64 * k]) * w0;
            }
        }
    }

    float se = 1.0f + eps[li];
    se = se > 0.0f ? se : 0.0f;           // relu(1+eps)
    float id = inv[n];
    const float* hr = h + (size_t)n * DIN;

    float pre[K];
#pragma unroll
    for (int k = 0; k < K; ++k) pre[k] = hr[lane + 64 * k] * se + pool[k] * id;

    if (!DO_MLP) {
        float* orow = out + (size_t)n * DIN;
#pragma unroll
        for (int k = 0; k < K; ++k) orow[lane + 64 * k] = pre[k];
        return;
    }

    float acc[DOUT / 64];
#pragma unroll
    for (int k = 0; k < DOUT / 64; ++k) acc[k] = b[lane + 64 * k];
#pragma unroll
    for (int d = 0; d < DIN; ++d) {
        float pd = __shfl(pre[d >> 6], d & 63);
#pragma unroll
        for (int k = 0; k < DOUT / 64; ++k)
            acc[k] += pd * W[d * DOUT + lane + 64 * k];
    }
    float* orow = out + (size_t)n * DOUT;
#pragma unroll
    for (int k = 0; k < DOUT / 64; ++k) {
        float v = acc[k];
        if (RELU) v = v > 0.0f ? v : 0.0f;
        orow[lane + 64 * k] = v;
    }
}

// ---- standalone per-row MLP (layer-2 tail; r7-proven) ----
template<int DIN, int DOUT, bool RELU>
__global__ __launch_bounds__(256) void k_mlp(const float* __restrict__ h,
                                             const float* __restrict__ W,
                                             const float* __restrict__ b,
                                             float* __restrict__ out) {
    int wave = threadIdx.x >> 6;
    int lane = threadIdx.x & 63;
    int n = blockIdx.x * (blockDim.x >> 6) + wave;
    if (n >= N_NODES) return;

    const float* hr = h + (size_t)n * DIN;
    float pre[DIN / 64];
#pragma unroll
    for (int k = 0; k < DIN / 64; ++k) pre[k] = hr[lane + 64 * k];

    float acc[DOUT / 64];
#pragma unroll
    for (int k = 0; k < DOUT / 64; ++k) acc[k] = b[lane + 64 * k];
#pragma unroll
    for (int d = 0; d < DIN; ++d) {
        float pd = __shfl(pre[d >> 6], d & 63);
#pragma unroll
        for (int k = 0; k < DOUT / 64; ++k)
            acc[k] += pd * W[d * DOUT + lane + 64 * k];
    }
    float* orow = out + (size_t)n * DOUT;
#pragma unroll
    for (int k = 0; k < DOUT / 64; ++k) {
        float v = acc[k];
        if (RELU) v = v > 0.0f ? v : 0.0f;
        orow[lane + 64 * k] = v;
    }
}

extern "C" void kernel_launch(void* const* d_in, const int* in_sizes, int n_in,
                              void* d_out, int out_size, void* d_ws, size_t ws_size,
                              hipStream_t stream) {
    const float* h0  = (const float*)d_in[0];
    const float* wts = (const float*)d_in[1];
    const int*   snd = (const int*)d_in[2];
    const int*   rcv = (const int*)d_in[3];
    const float* W0  = (const float*)d_in[4];
    const float* b0  = (const float*)d_in[5];
    const float* W1  = (const float*)d_in[6];
    const float* b1  = (const float*)d_in[7];
    const float* W2  = (const float*)d_in[8];
    const float* b2  = (const float*)d_in[9];
    const float* eps = (const float*)d_in[10];

    float* out0 = (float*)d_out;                  // node_embeddings
    float* out1 = out0 + (size_t)N_NODES * D_HID; // final h

    // ws layout (~20 MB): deg|bsum|boff|off|cursor|inv|e_snd|e_w|hb
    int*   deg    = (int*)d_ws;
    int*   bsum   = deg + N_NODES;
    int*   boff   = bsum + 256;
    int*   off    = boff + 256;
    int*   cursor = off + N_NODES + 2;
    float* inv    = (float*)(cursor + N_NODES);
    int*   e_snd  = (int*)(inv + N_NODES);
    float* e_w    = (float*)(e_snd + N_EDGES);
    unsigned int* hb32 = (unsigned int*)(e_w + N_EDGES);   // bf16 rows, pair-packed
    unsigned short* hb = (unsigned short*)hb32;

    hipMemsetAsync(deg, 0, (size_t)N_NODES * sizeof(int), stream);
    k_count<<<(N_EDGES + 255) / 256, 256, 0, stream>>>(rcv, deg);
    k_blocksum<<<NBLK, 256, 0, stream>>>(deg, bsum);
    k_scanb<<<1, 256, 0, stream>>>(bsum, boff);
    k_offsets<<<NBLK, 256, 0, stream>>>(deg, boff, off, cursor, inv);
    k_fill<<<(N_EDGES + 255) / 256, 256, 0, stream>>>(snd, rcv, wts, cursor, e_snd, e_w);

    // L0: h0(64) -> out0(128), relu
    {
        int np = N_NODES * D_IN / 2;
        k_tobf<<<(np + 255) / 256, 256, 0, stream>>>(h0, hb32, np);
    }
    k_layer<D_IN, D_HID, true, true><<<N_NODES / 4, 256, 0, stream>>>(
        h0, hb, off, e_snd, e_w, inv, eps, 0, W0, b0, out0);

    // L1: out0 -> out1, relu
    {
        int np = N_NODES * D_HID / 2;
        k_tobf<<<(np + 255) / 256, 256, 0, stream>>>(out0, hb32, np);
    }
    k_layer<D_HID, D_HID, true, true><<<N_NODES / 4, 256, 0, stream>>>(
        out0, hb, off, e_snd, e_w, inv, eps, 1, W1, b1, out1);

    // L2a: gather+update only: out1 -> out0 (= node_embeddings)
    {
        int np = N_NODES * D_HID / 2;
        k_tobf<<<(np + 255) / 256, 256, 0, stream>>>(out1, hb32, np);
    }
    k_layer<D_HID, D_HID, false, false><<<N_NODES / 4, 256, 0, stream>>>(
        out1, hb, off, e_snd, e_w, inv, eps, 2, nullptr, nullptr, out0);

    // L2b: final MLP (no relu): out0 -> out1
    k_mlp<D_HID, D_HID, false><<<N_NODES / 4, 256, 0, stream>>>(out0, W2, b2, out1);
}

// Round 14
// 476.118 us; speedup vs baseline: 2.4931x; 2.4931x over previous
//
#include <hip/hip_runtime.h>

#define N_NODES 50000
#define N_EDGES 800000
#define D_IN    64
#define D_HID   128
#define NBLK    ((N_NODES + 255) / 256)   // 196

__device__ __forceinline__ float bf2f(unsigned short u) {
    return __uint_as_float(((unsigned)u) << 16);
}
__device__ __forceinline__ unsigned short f2bf(float f) {
    unsigned u = __float_as_uint(f);
    return (unsigned short)((u + 0x7FFFu + ((u >> 16) & 1u)) >> 16);
}

// ---- CSR build ----
__global__ void k_count(const int* __restrict__ rcv, int* __restrict__ deg) {
    int i = blockIdx.x * blockDim.x + threadIdx.x;
    if (i < N_EDGES) atomicAdd(&deg[rcv[i]], 1);
}

__global__ void k_blocksum(const int* __restrict__ deg, int* __restrict__ bsum) {
    int b = blockIdx.x, t = threadIdx.x;
    int i = b * 256 + t;
    int v = (i < N_NODES) ? deg[i] : 0;
#pragma unroll
    for (int o = 32; o >= 1; o >>= 1) v += __shfl_down(v, o);
    __shared__ int s[4];
    if ((t & 63) == 0) s[t >> 6] = v;
    __syncthreads();
    if (t == 0) bsum[b] = s[0] + s[1] + s[2] + s[3];
}

__global__ void k_scanb(const int* __restrict__ bsum, int* __restrict__ boff) {
    __shared__ int sh[256];
    int t = threadIdx.x;
    int v = (t < NBLK) ? bsum[t] : 0;
    sh[t] = v;
    __syncthreads();
    for (int d = 1; d < 256; d <<= 1) {
        int u = (t >= d) ? sh[t - d] : 0;
        __syncthreads();
        sh[t] += u;
        __syncthreads();
    }
    boff[t] = sh[t] - v;   // exclusive
}

__global__ void k_offsets(const int* __restrict__ deg, const int* __restrict__ boff,
                          int* __restrict__ off, int* __restrict__ cursor,
                          float* __restrict__ inv) {
    __shared__ int sh[256];
    int b = blockIdx.x, t = threadIdx.x, i = b * 256 + t;
    int d = (i < N_NODES) ? deg[i] : 0;
    sh[t] = d;
    __syncthreads();
    for (int o = 1; o < 256; o <<= 1) {
        int u = (t >= o) ? sh[t - o] : 0;
        __syncthreads();
        sh[t] += u;
        __syncthreads();
    }
    if (i < N_NODES) {
        int excl = boff[b] + sh[t] - d;
        off[i] = excl;
        cursor[i] = excl;
        inv[i] = d > 0 ? 1.0f / (float)d : 0.0f;
    }
    if (b == 0 && t == 0) off[N_NODES] = N_EDGES;
}

__global__ void k_fill(const int* __restrict__ snd, const int* __restrict__ rcv,
                       const float* __restrict__ w,
                       int* __restrict__ cursor,
                       int* __restrict__ e_snd, float* __restrict__ e_w) {
    int i = blockIdx.x * blockDim.x + threadIdx.x;
    if (i >= N_EDGES) return;
    int r = rcv[i];
    int p = atomicAdd(&cursor[r], 1);
    e_snd[p] = snd[i];
    e_w[p]   = w[i];
}

// ---- fp32 -> bf16 (RNE) pair-packed conversion ----
__global__ void k_tobf(const float* __restrict__ src, unsigned int* __restrict__ dst,
                       int npairs) {
    int i = blockIdx.x * blockDim.x + threadIdx.x;
    if (i >= npairs) return;
    float2 v = *(const float2*)(src + (size_t)i * 2);
    dst[i] = (unsigned)f2bf(v.x) | ((unsigned)f2bf(v.y) << 16);
}

// ---- fused layer (r7-proven access pattern; hb now 256B-aligned) ----
// One wave per node; lane l holds feature(s) l (+64k). Neighbor rows read from
// bf16 copy hb; residual + MLP in fp32. With hb 256B-aligned, each 128B
// half-row load hits exactly one cache line (was 2 when misaligned).
template<int DIN, int DOUT, bool RELU, bool DO_MLP>
__global__ __launch_bounds__(256) void k_layer(
        const float* __restrict__ h,
        const unsigned short* __restrict__ hb,
        const int* __restrict__ off,
        const int* __restrict__ e_snd,
        const float* __restrict__ e_w,
        const float* __restrict__ inv,
        const float* __restrict__ eps, int li,
        const float* __restrict__ W,
        const float* __restrict__ b,
        float* __restrict__ out) {
    constexpr int K = DIN / 64;
    int wave = threadIdx.x >> 6;
    int lane = threadIdx.x & 63;
    int n = blockIdx.x * (blockDim.x >> 6) + wave;
    if (n >= N_NODES) return;

    float pool[K];
#pragma unroll
    for (int k = 0; k < K; ++k) pool[k] = 0.0f;

    int e0 = off[n], e1 = off[n + 1];
    int e = e0;
    for (; e + 1 < e1; e += 2) {          // unroll-2 for load ILP
        int s0 = e_snd[e], s1 = e_snd[e + 1];
        float w0 = e_w[e], w1 = e_w[e + 1];
        const unsigned short* p0 = hb + (size_t)s0 * DIN;
        const unsigned short* p1 = hb + (size_t)s1 * DIN;
        float a0[K], a1[K];
#pragma unroll
        for (int k = 0; k < K; ++k) { a0[k] = bf2f(p0[lane + 64 * k]); a1[k] = bf2f(p1[lane + 64 * k]); }
#pragma unroll
        for (int k = 0; k < K; ++k) pool[k] += a0[k] * w0 + a1[k] * w1;
    }
    if (e < e1) {
        int s0 = e_snd[e]; float w0 = e_w[e];
        const unsigned short* p0 = hb + (size_t)s0 * DIN;
#pragma unroll
        for (int k = 0; k < K; ++k) pool[k] += bf2f(p0[lane + 64 * k]) * w0;
    }

    float se = 1.0f + eps[li];
    se = se > 0.0f ? se : 0.0f;           // relu(1+eps)
    float id = inv[n];
    const float* hr = h + (size_t)n * DIN;

    float pre[K];
#pragma unroll
    for (int k = 0; k < K; ++k) pre[k] = hr[lane + 64 * k] * se + pool[k] * id;

    if (!DO_MLP) {
        float* orow = out + (size_t)n * DIN;
#pragma unroll
        for (int k = 0; k < K; ++k) orow[lane + 64 * k] = pre[k];
        return;
    }

    float acc[DOUT / 64];
#pragma unroll
    for (int k = 0; k < DOUT / 64; ++k) acc[k] = b[lane + 64 * k];
#pragma unroll
    for (int d = 0; d < DIN; ++d) {
        float pd = __shfl(pre[d >> 6], d & 63);
#pragma unroll
        for (int k = 0; k < DOUT / 64; ++k)
            acc[k] += pd * W[d * DOUT + lane + 64 * k];
    }
    float* orow = out + (size_t)n * DOUT;
#pragma unroll
    for (int k = 0; k < DOUT / 64; ++k) {
        float v = acc[k];
        if (RELU) v = v > 0.0f ? v : 0.0f;
        orow[lane + 64 * k] = v;
    }
}

// ---- standalone per-row MLP (layer-2 tail; r7-proven) ----
template<int DIN, int DOUT, bool RELU>
__global__ __launch_bounds__(256) void k_mlp(const float* __restrict__ h,
                                             const float* __restrict__ W,
                                             const float* __restrict__ b,
                                             float* __restrict__ out) {
    int wave = threadIdx.x >> 6;
    int lane = threadIdx.x & 63;
    int n = blockIdx.x * (blockDim.x >> 6) + wave;
    if (n >= N_NODES) return;

    const float* hr = h + (size_t)n * DIN;
    float pre[DIN / 64];
#pragma unroll
    for (int k = 0; k < DIN / 64; ++k) pre[k] = hr[lane + 64 * k];

    float acc[DOUT / 64];
#pragma unroll
    for (int k = 0; k < DOUT / 64; ++k) acc[k] = b[lane + 64 * k];
#pragma unroll
    for (int d = 0; d < DIN; ++d) {
        float pd = __shfl(pre[d >> 6], d & 63);
#pragma unroll
        for (int k = 0; k < DOUT / 64; ++k)
            acc[k] += pd * W[d * DOUT + lane + 64 * k];
    }
    float* orow = out + (size_t)n * DOUT;
#pragma unroll
    for (int k = 0; k < DOUT / 64; ++k) {
        float v = acc[k];
        if (RELU) v = v > 0.0f ? v : 0.0f;
        orow[lane + 64 * k] = v;
    }
}

extern "C" void kernel_launch(void* const* d_in, const int* in_sizes, int n_in,
                              void* d_out, int out_size, void* d_ws, size_t ws_size,
                              hipStream_t stream) {
    const float* h0  = (const float*)d_in[0];
    const float* wts = (const float*)d_in[1];
    const int*   snd = (const int*)d_in[2];
    const int*   rcv = (const int*)d_in[3];
    const float* W0  = (const float*)d_in[4];
    const float* b0  = (const float*)d_in[5];
    const float* W1  = (const float*)d_in[6];
    const float* b1  = (const float*)d_in[7];
    const float* W2  = (const float*)d_in[8];
    const float* b2  = (const float*)d_in[9];
    const float* eps = (const float*)d_in[10];

    float* out0 = (float*)d_out;                  // node_embeddings
    float* out1 = out0 + (size_t)N_NODES * D_HID; // final h

    // ws layout (~20 MB), every array 256B-aligned (hb alignment is the fix:
    // it was 8 mod 128 -> every row-load spanned an extra cache line).
    uintptr_t base = (uintptr_t)d_ws;
    auto al = [&](uintptr_t& p, size_t bytes) {
        p = (p + 255) & ~(uintptr_t)255;
        uintptr_t r = p;
        p += bytes;
        return r;
    };
    uintptr_t cur = base;
    int*   deg    = (int*)  al(cur, (size_t)N_NODES * 4);
    int*   bsum   = (int*)  al(cur, 256 * 4);
    int*   boff   = (int*)  al(cur, 256 * 4);
    int*   off    = (int*)  al(cur, (size_t)(N_NODES + 1) * 4);
    int*   cursor = (int*)  al(cur, (size_t)N_NODES * 4);
    float* inv    = (float*)al(cur, (size_t)N_NODES * 4);
    int*   e_snd  = (int*)  al(cur, (size_t)N_EDGES * 4);
    float* e_w    = (float*)al(cur, (size_t)N_EDGES * 4);
    unsigned int* hb32 = (unsigned int*)al(cur, (size_t)N_NODES * D_HID * 2);
    unsigned short* hb = (unsigned short*)hb32;

    hipMemsetAsync(deg, 0, (size_t)N_NODES * sizeof(int), stream);
    k_count<<<(N_EDGES + 255) / 256, 256, 0, stream>>>(rcv, deg);
    k_blocksum<<<NBLK, 256, 0, stream>>>(deg, bsum);
    k_scanb<<<1, 256, 0, stream>>>(bsum, boff);
    k_offsets<<<NBLK, 256, 0, stream>>>(deg, boff, off, cursor, inv);
    k_fill<<<(N_EDGES + 255) / 256, 256, 0, stream>>>(snd, rcv, wts, cursor, e_snd, e_w);

    // L0: h0(64) -> out0(128), relu
    {
        int np = N_NODES * D_IN / 2;
        k_tobf<<<(np + 255) / 256, 256, 0, stream>>>(h0, hb32, np);
    }
    k_layer<D_IN, D_HID, true, true><<<N_NODES / 4, 256, 0, stream>>>(
        h0, hb, off, e_snd, e_w, inv, eps, 0, W0, b0, out0);

    // L1: out0 -> out1, relu
    {
        int np = N_NODES * D_HID / 2;
        k_tobf<<<(np + 255) / 256, 256, 0, stream>>>(out0, hb32, np);
    }
    k_layer<D_HID, D_HID, true, true><<<N_NODES / 4, 256, 0, stream>>>(
        out0, hb, off, e_snd, e_w, inv, eps, 1, W1, b1, out1);

    // L2a: gather+update only: out1 -> out0 (= node_embeddings)
    {
        int np = N_NODES * D_HID / 2;
        k_tobf<<<(np + 255) / 256, 256, 0, stream>>>(out1, hb32, np);
    }
    k_layer<D_HID, D_HID, false, false><<<N_NODES / 4, 256, 0, stream>>>(
        out1, hb, off, e_snd, e_w, inv, eps, 2, nullptr, nullptr, out0);

    // L2b: final MLP (no relu): out0 -> out1
    k_mlp<D_HID, D_HID, false><<<N_NODES / 4, 256, 0, stream>>>(out0, W2, b2, out1);
}